// Round 2
// baseline (1410.223 us; speedup 1.0000x reference)
//
#include <hip/hip_runtime.h>
#include <hip/hip_cooperative_groups.h>

namespace cg = cooperative_groups;

// GnnEmbedder: two-part embedding -> SAGEConv(mean) x2. f32 at the edges,
// bf16 internally (threshold 2% relative; bf16 path error ~3e-4).
// R2: single cooperative mega-kernel (zero-cnt | gsync | scatter+embed+prep |
// gsync | layer1 | gsync | layer2). Eliminates 4 dispatch drains + memset
// dispatch; gather uses coalesced index loads + shfl broadcast with a 1-row
// software pipeline. Non-cooperative 4-dispatch fallback if coop launch is
// rejected. Diagnostic goal: mega-kernel MUST show in top-5 counters next
// round, separating our time from the 2 GB poison-fill floor (~313-460 us).

#define N_CLIENTS 1000000
#define N_NODES   100000
#define N_EDGES   1600000
#define DCAP      64      // in-degree ~ Poisson(16); P(deg>64) ~ e^-125
#define NTILES    1563    // ceil(N_NODES / 64)

typedef unsigned short u16;
typedef unsigned int   u32;
typedef __bf16  bf16x8 __attribute__((ext_vector_type(8)));
typedef float   f32x4  __attribute__((ext_vector_type(4)));

__device__ __forceinline__ u16 f2bf(float f) {
    union { float f; u32 i; } c; c.f = f;
    u32 r = c.i + 0x7FFFu + ((c.i >> 16) & 1u);   // RNE
    return (u16)(r >> 16);
}
__device__ __forceinline__ float2 bfpair(u32 u) {   // low short = elem 0
    union { u32 i; float f; } lo, hi;
    lo.i = u << 16; hi.i = u & 0xFFFF0000u;
    return make_float2(lo.f, hi.f);
}

// ---- front phase: scatter + embed + prep, all grid-stride ------------------
__device__ __forceinline__ void phase_front(
    const float* __restrict__ client, const float* __restrict__ item,
    const int* __restrict__ ids,
    const int* __restrict__ src, const int* __restrict__ dst,
    const float* __restrict__ W0, const float* __restrict__ W1,
    const float* __restrict__ W2, const float* __restrict__ W3,
    u16* __restrict__ Xb, int* __restrict__ cnt, int* __restrict__ bucket,
    u16* __restrict__ Wt)
{
    int gtid = blockIdx.x * 256 + threadIdx.x;
    int gs = gridDim.x * 256;
    // scatter: cnt[dst]++ ; bucket[dst][pos] = src
    for (int e = gtid; e < N_EDGES; e += gs) {
        int d = dst[e];
        int pos = atomicAdd(&cnt[d], 1);
        if (pos < DCAP) bucket[(size_t)d * DCAP + pos] = src[e];
    }
    // embed: gather f32 row (512 B), convert, store bf16 row (256 B)
    for (int t = gtid; t < N_NODES * 32; t += gs) {
        int node = t >> 5, j = t & 31;                 // 32 thr x float4 per row
        int id = ids[node];
        const float4* row = (id < N_CLIENTS)
            ? (const float4*)(client + (size_t)id * 128)
            : (const float4*)(item + (size_t)(id - N_CLIENTS) * 128);
        float4 v = row[j];
        uint2 o;
        o.x = ((u32)f2bf(v.y) << 16) | f2bf(v.x);
        o.y = ((u32)f2bf(v.w) << 16) | f2bf(v.z);
        *(uint2*)(Xb + (size_t)node * 128 + j * 4) = o;
    }
    // prep: Wt[mat][n][k] bf16 = W[mat][k][n] f32 (4 mats, 128x128)
    for (int i = gtid; i < 65536; i += gs) {
        int mat = i >> 14, k = (i >> 7) & 127, n = i & 127;
        const float* W = mat == 0 ? W0 : mat == 1 ? W1 : mat == 2 ? W2 : W3;
        Wt[mat * 16384 + n * 128 + k] = f2bf(W[k * 128 + n]);
    }
}

// ---- fused layer: out = act(x@Ws + mean_agg(x)@Wn + b), 64 rows/tile -------
// mfma_f32_16x16x32_bf16: A[m=lane&15][k=(lane>>4)*8+j];
// B[k][n=lane&15] (Wt is [n][k]); C/D col=lane&15, row=(lane>>4)*4+reg.
// LDS weight stride 144 u16 (18 granules), hn stride 136 u16 (17 granules):
// conflict-free b128 (SQ_LDS_BANK_CONFLICT measured 0).
// Gather: degree counts hoisted via one 64B coalesced load + shfl; each row's
// 64 bucket indices via one 256B coalesced load, broadcast with shfl;
// next row's index load overlaps current row's gathers (1-deep pipeline).
__device__ void layer_tiles(
    const u16* __restrict__ Xin,
    const int* __restrict__ cnt, const int* __restrict__ bucket,
    const u16* __restrict__ Wts, const u16* __restrict__ Wtn,
    const float* __restrict__ bias,
    u16* __restrict__ OUTb, float* __restrict__ OUTf, int relu,
    u16* wlds, u16* hnl)
{
    int tid = threadIdx.x;
    int w = tid >> 6, lane = tid & 63;
    int m = lane & 15, q = lane >> 4;
    for (int tile = blockIdx.x; tile < NTILES; tile += gridDim.x) {
        int r0 = tile * 64;
        // stage Ws early (loads overlap the gather; consumed after sync)
        for (int i = tid; i < 128 * 16; i += 256) {
            int n = i >> 4, c8 = i & 15;
            *(uint4*)&wlds[n * 144 + c8 * 8] = *(const uint4*)(Wts + n * 128 + c8 * 8);
        }
        int rowa = r0 + w * 16 + m;
        int rowc = rowa < N_NODES ? rowa : N_NODES - 1;
        bf16x8 ax[4];
        #pragma unroll
        for (int kc = 0; kc < 4; ++kc)
            ax[kc] = *(const bf16x8*)(Xin + (size_t)rowc * 128 + kc * 32 + q * 8);

        // hoist this wave's 16 degree counts (one coalesced 64B load)
        int crow = r0 + w * 16 + (lane & 15);
        int crowc = crow < N_NODES ? crow : N_NODES - 1;
        int dall = cnt[crowc];
        int rv0 = r0 + w * 16;
        int dv0 = rv0 < N_NODES ? rv0 : N_NODES - 1;
        int srcs = bucket[(size_t)dv0 * DCAP + lane];   // row 0 indices (256B)
        for (int rr = 0; rr < 16; ++rr) {
            int d = __shfl(dall, rr);
            int dc = d < DCAP ? d : DCAP;
            int nsrcs = 0;
            if (rr < 15) {                              // prefetch next row's indices
                int nr = r0 + w * 16 + rr + 1;
                int nv = nr < N_NODES ? nr : N_NODES - 1;
                nsrcs = bucket[(size_t)nv * DCAP + lane];
            }
            float sx = 0.f, sy = 0.f;
            int e = 0;
            for (; e + 8 <= dc; e += 8) {
                u32 uu[8];
                #pragma unroll
                for (int z = 0; z < 8; ++z) {
                    int s = __shfl(srcs, e + z);
                    uu[z] = *(const u32*)(Xin + (size_t)s * 128 + lane * 2);
                }
                #pragma unroll
                for (int z = 0; z < 8; ++z) {
                    float2 v = bfpair(uu[z]);
                    sx += v.x; sy += v.y;
                }
            }
            for (; e < dc; ++e) {
                int s = __shfl(srcs, e);
                float2 v = bfpair(*(const u32*)(Xin + (size_t)s * 128 + lane * 2));
                sx += v.x; sy += v.y;
            }
            float inv = 1.0f / fmaxf((float)d, 1.0f);
            *(u32*)&hnl[(w * 16 + rr) * 136 + lane * 2] =
                ((u32)f2bf(sy * inv) << 16) | f2bf(sx * inv);
            srcs = nsrcs;
        }
        __syncthreads();                                // wlds staged + hnl done

        bf16x8 ah[4];
        #pragma unroll
        for (int kc = 0; kc < 4; ++kc)
            ah[kc] = *(const bf16x8*)&hnl[(w * 16 + m) * 136 + kc * 32 + q * 8];

        f32x4 acc[8];
        #pragma unroll
        for (int t = 0; t < 8; ++t) {
            float bv = bias[t * 16 + m];
            acc[t] = (f32x4){bv, bv, bv, bv};
        }
        // phase 1: x @ Ws
        #pragma unroll
        for (int kc = 0; kc < 4; ++kc)
            #pragma unroll
            for (int t = 0; t < 8; ++t) {
                bf16x8 bfr = *(const bf16x8*)&wlds[(t * 16 + m) * 144 + kc * 32 + q * 8];
                acc[t] = __builtin_amdgcn_mfma_f32_16x16x32_bf16(ax[kc], bfr, acc[t], 0, 0, 0);
            }
        __syncthreads();
        // phase 2: hn @ Wn (re-stage same LDS)
        for (int i = tid; i < 128 * 16; i += 256) {
            int n = i >> 4, c8 = i & 15;
            *(uint4*)&wlds[n * 144 + c8 * 8] = *(const uint4*)(Wtn + n * 128 + c8 * 8);
        }
        __syncthreads();
        #pragma unroll
        for (int kc = 0; kc < 4; ++kc)
            #pragma unroll
            for (int t = 0; t < 8; ++t) {
                bf16x8 bfr = *(const bf16x8*)&wlds[(t * 16 + m) * 144 + kc * 32 + q * 8];
                acc[t] = __builtin_amdgcn_mfma_f32_16x16x32_bf16(ah[kc], bfr, acc[t], 0, 0, 0);
            }
        // epilogue: C/D row = w*16 + q*4 + reg, col = t*16 + m
        #pragma unroll
        for (int t = 0; t < 8; ++t) {
            int col = t * 16 + m;
            #pragma unroll
            for (int r = 0; r < 4; ++r) {
                int row = r0 + w * 16 + q * 4 + r;
                if (row < N_NODES) {
                    float v = acc[t][r];
                    if (relu) v = fmaxf(v, 0.f);
                    if (OUTb) OUTb[(size_t)row * 128 + col] = f2bf(v);
                    else      OUTf[(size_t)row * 128 + col] = v;
                }
            }
        }
        __syncthreads();                                // protect wlds/hnl reuse
    }
}

// ---- the mega-kernel (cooperative) ----------------------------------------
__global__ __launch_bounds__(256, 3) void mega_kernel(
    const float* client, const float* item,
    const float* W0, const float* W1, const float* W2, const float* W3,
    const float* b1, const float* b2,
    const int* ids, const int* src, const int* dst,
    u16* xb, u16* hb, int* cnt, int* bucket, u16* Wt, float* out)
{
    __shared__ u16 wlds[128 * 144];                    // 36,864 B
    __shared__ u16 hnl[64 * 136];                      // 17,408 B (54.3 KB -> 3 blk/CU)
    cg::grid_group grid = cg::this_grid();
    int gtid = blockIdx.x * 256 + threadIdx.x;
    int gs = gridDim.x * 256;
    for (int i = gtid; i < N_NODES; i += gs) cnt[i] = 0;
    grid.sync();
    phase_front(client, item, ids, src, dst, W0, W1, W2, W3, xb, cnt, bucket, Wt);
    grid.sync();
    layer_tiles(xb, cnt, bucket, Wt, Wt + 16384, b1, hb, (float*)nullptr, 1, wlds, hnl);
    grid.sync();
    layer_tiles(hb, cnt, bucket, Wt + 32768, Wt + 49152, b2, (u16*)nullptr, out, 0, wlds, hnl);
}

// ---- non-cooperative fallback ---------------------------------------------
__global__ __launch_bounds__(256) void front_kernel(
    const float* client, const float* item,
    const float* W0, const float* W1, const float* W2, const float* W3,
    const int* ids, const int* src, const int* dst,
    u16* xb, int* cnt, int* bucket, u16* Wt)
{
    phase_front(client, item, ids, src, dst, W0, W1, W2, W3, xb, cnt, bucket, Wt);
}

__global__ __launch_bounds__(256, 3) void layer_kernel(
    const u16* Xin, const int* cnt, const int* bucket,
    const u16* Wts, const u16* Wtn, const float* bias,
    u16* OUTb, float* OUTf, int relu)
{
    __shared__ u16 wlds[128 * 144];
    __shared__ u16 hnl[64 * 136];
    layer_tiles(Xin, cnt, bucket, Wts, Wtn, bias, OUTb, OUTf, relu, wlds, hnl);
}

extern "C" void kernel_launch(void* const* d_in, const int* in_sizes, int n_in,
                              void* d_out, int out_size, void* d_ws, size_t ws_size,
                              hipStream_t stream) {
    const float* client = (const float*)d_in[0];
    const float* item   = (const float*)d_in[1];
    const float* Ws1    = (const float*)d_in[2];
    const float* Wn1    = (const float*)d_in[3];
    const float* b1     = (const float*)d_in[4];
    const float* Ws2    = (const float*)d_in[5];
    const float* Wn2    = (const float*)d_in[6];
    const float* b2     = (const float*)d_in[7];
    const int* node_ids = (const int*)d_in[8];
    const int* src      = (const int*)d_in[9];
    const int* dst      = (const int*)d_in[10];
    float* out = (float*)d_out;

    // ws: xb 25.6MB | hb 25.6MB | cnt 0.4MB | bucket 25.6MB | Wt 128KB
    char* ws = (char*)d_ws;
    u16* xb     = (u16*)ws;
    u16* hb     = (u16*)(ws + 25600000);
    int* cnt    = (int*)(ws + 51200000);
    int* bucket = (int*)(ws + 51600000);
    u16* Wt     = (u16*)(ws + 77200000);

    static int coopGrid = -2;          // -2 = unqueried, -1 = fallback
    if (coopGrid == -2) {
        int maxb = 0;
        if (hipOccupancyMaxActiveBlocksPerMultiprocessor(
                &maxb, (const void*)mega_kernel, 256, 0) == hipSuccess && maxb > 0) {
            coopGrid = maxb * 256;     // 256 CUs on MI355X
            if (coopGrid > 2048) coopGrid = 2048;
        } else {
            coopGrid = -1;
        }
    }

    if (coopGrid > 0) {
        void* args[] = {
            (void*)&client, (void*)&item,
            (void*)&Ws1, (void*)&Wn1, (void*)&Ws2, (void*)&Wn2,
            (void*)&b1, (void*)&b2,
            (void*)&node_ids, (void*)&src, (void*)&dst,
            (void*)&xb, (void*)&hb, (void*)&cnt, (void*)&bucket,
            (void*)&Wt, (void*)&out
        };
        hipError_t err = hipLaunchCooperativeKernel(
            (const void*)mega_kernel, dim3(coopGrid), dim3(256),
            args, 0, stream);
        if (err == hipSuccess) return;
        coopGrid = -1;                 // launch rejected: permanent fallback
    }

    // fallback: 4 plain dispatches (same device code paths)
    hipMemsetAsync(cnt, 0, N_NODES * sizeof(int), stream);
    front_kernel<<<2048, 256, 0, stream>>>(client, item, Ws1, Wn1, Ws2, Wn2,
                                           node_ids, src, dst, xb, cnt, bucket, Wt);
    layer_kernel<<<NTILES, 256, 0, stream>>>(xb, cnt, bucket, Wt, Wt + 16384,
                                             b1, hb, (float*)nullptr, 1);
    layer_kernel<<<NTILES, 256, 0, stream>>>(hb, cnt, bucket, Wt + 32768, Wt + 49152,
                                             b2, (u16*)nullptr, out, 0);
}